// Round 1
// 10.321 us; speedup vs baseline: 1.4449x; 1.4449x over previous
//
#include <hip/hip_runtime.h>

// Parzen-window histogram density, B=2, N=2, NUM_BINS=16, RADIUS=2, K=20.
//
// Bit-exact floor path (knife edge at 2/18 on every voxel):
//  * r = cr32(1/bws) via IEEE correctly-rounded f32 divide (hipcc default:
//    -fhip-fp32-correctly-rounded-divide-sqrt). Identical to the previous
//    f64-Newton recip_cr32: exact ties cannot occur (16/c is never a
//    25-bit dyadic rational), so RN == the old round-half-up fixup.
//  * q = a * r: single native f32 mul.
//
// FAST PATH (all non-degenerate voxels: floor(q) in [1,18], windows >=5
// bins apart so no cross-window histogram hits): the 4 window tap weights
// are a shifted view of one basis on the exact fractional part
// u = q - floor(q):
//    W0'=(1-u)^3  W1'=3u^3-6u^2+4  W2'=3(1-u)^3-6(1-u)^2+4  W3'=u^3
// (shift s in {-1,0,+1} for fq in {1,[2..17],18}; shifted-out tap = 0),
// and the gathered weight is ALWAYS W1' (i - base - s == 1). u, 1-u and
// all tap offsets are exact f32 subtractions; polynomial source forms are
// verbatim from bsplinef so contraction/rounding matches the reference.
// The common *(1/6) cancels between numerator and denominator (<=2^-23
// rel. error; final divide already uses 1-ulp rcpf, "bf16-safe").
//
// SLOW PATH (degenerate: |x0-x1| ~ 1e-7 clamped bin width, or rounding
// pushes q outside [1,19)): the previous fully-general per-tap piecewise
// code, verified absmax=0.0 in the prior session (R8).

typedef float f32x4 __attribute__((ext_vector_type(4)));

__device__ __forceinline__ float bsplinef(float d) {
    float ad = fabsf(d);
    float ad2 = ad * ad;
    float wi = (3.0f * ad2 * ad - 6.0f * ad2 + 4.0f) * (1.0f / 6.0f);
    float t = 2.0f - ad;
    float wo = (t * t * t) * (1.0f / 6.0f);
    float w = ad < 1.0f ? wi : wo;
    return ad < 2.0f ? w : 0.0f;
}

__device__ __forceinline__ void parzen_pair(float x0, float x1, float m0, float m1,
                                            float& o0, float& o1) {
    float mx  = fmaxf(x0, x1);
    float mn  = fminf(x0, x1);
    float c   = mx - mn;               // single cr32 sub
    float bw  = c * 0.0625f;           // exact (/16)
    float b2  = bw + bw;               // exact
    float pad = mn - b2;               // single cr32 sub
    float bws = fmaxf(bw, 1e-8f);
    float r   = 1.0f / bws;            // IEEE correctly-rounded: cr32(1/bws)
    float a0  = x0 - pad;              // single cr32 sub
    float a1  = x1 - pad;
    float q0  = a0 * r;                // bin_pos = fl32(a*r)
    float q1  = a1 * r;
    float qf0 = floorf(q0);
    float qf1 = floorf(q1);

    bool fast = (qf0 >= 1.0f) & (qf0 <= 18.0f) & (qf1 >= 1.0f) & (qf1 <= 18.0f)
              & (fabsf(qf0 - qf1) >= 5.0f);
    if (__builtin_expect(fast, 1)) {
        float u0 = q0 - qf0;                 // exact: frac part, in [0,1)
        float u1 = q1 - qf1;
        float v0 = 1.0f - u0;                // exact
        float u0s = u0 * u0, v0s = v0 * v0;
        float A0 = v0s * v0;                                  // outer(1+u)*6
        float A1 = 3.0f * u0s * u0 - 6.0f * u0s + 4.0f;       // inner(u)*6
        float A2 = 3.0f * v0s * v0 - 6.0f * v0s + 4.0f;       // inner(1-u)*6
        float A3 = u0s * u0;                                  // outer(2-u)*6
        float v1 = 1.0f - u1;
        float u1s = u1 * u1, v1s = v1 * v1;
        float B0 = v1s * v1;
        float B1 = 3.0f * u1s * u1 - 6.0f * u1s + 4.0f;
        float B2 = 3.0f * v1s * v1 - 6.0f * v1s + 4.0f;
        float B3 = u1s * u1;
        float dA = (A0 + A1) + (A2 + A3);
        float dB = (B0 + B1) + (B2 + B3);
        // shift: fq==18 -> window {16..19}, tap W3' falls off the top;
        //        fq==1  -> window { 1..4 }, tap W0' falls off the bottom.
        float dropA = (qf0 > 17.5f) ? A3 : ((qf0 < 1.5f) ? A0 : 0.0f);
        float dropB = (qf1 > 17.5f) ? B3 : ((qf1 < 1.5f) ? B0 : 0.0f);
        float denom = (dA - dropA) + (dB - dropB);   // >= A1+B1 >= 2, no clamp needed
        float rd = __builtin_amdgcn_rcpf(denom);     // 1 ulp; bf16-safe
        o0 = (m0 != 0.0f) ? (A1 * rd) : 0.0f;        // gathered tap is always W1'
        o1 = (m1 != 0.0f) ? (B1 * rd) : 0.0f;
    } else {
        // fully-general exact path (rare: degenerate / clamped voxels)
        int fq0 = (int)fminf(fmaxf(qf0, 0.0f), 20.0f);
        int fq1 = (int)fminf(fmaxf(qf1, 0.0f), 20.0f);
        int base0 = min(max(fq0, 2), 17) - 1;   // hist window {base..base+3}
        int base1 = min(max(fq1, 2), 17) - 1;
        int i0 = min(fq0, 19);                  // gather bin per image
        int i1 = min(fq1, 19);

        float h0 = 0.0f, h1 = 0.0f, denom = 0.0f;
#pragma unroll
        for (int k = 0; k < 4; ++k) {           // per-tap piecewise eval (exact)
            float wa = bsplinef(q0 - (float)(base0 + k));
            float wb = bsplinef(q1 - (float)(base1 + k));
            denom += wa;
            denom += wb;
            h0 += (base0 + k == i0) ? wa : 0.0f;
            h0 += (base1 + k == i0) ? wb : 0.0f;
            h1 += (base0 + k == i1) ? wa : 0.0f;
            h1 += (base1 + k == i1) ? wb : 0.0f;
        }
        float dc = fmaxf(denom, 1e-8f);
        float rd = __builtin_amdgcn_rcpf(dc);
        o0 = (m0 != 0.0f) ? (h0 * rd) : 0.0f;
        o1 = (m1 != 0.0f) ? (h1 * rd) : 0.0f;
    }
}

__global__ __launch_bounds__(256) void parzen_kernel(
    const float* __restrict__ img, const float* __restrict__ mask,
    float* __restrict__ out, int V) {
    const int V4 = V >> 2;
    int t = blockIdx.x * blockDim.x + threadIdx.x;
    if (t >= 2 * V4) return;               // B = 2
    int b = (t >= V4) ? 1 : 0;
    int v = (t - b * V4) << 2;

    size_t off0 = (size_t)(b * 2 + 0) * (size_t)V + (size_t)v;  // n = 0
    size_t off1 = (size_t)(b * 2 + 1) * (size_t)V + (size_t)v;  // n = 1

    const float4 X0 = *reinterpret_cast<const float4*>(img  + off0);
    const float4 X1 = *reinterpret_cast<const float4*>(img  + off1);
    const float4 M0 = *reinterpret_cast<const float4*>(mask + off0);
    const float4 M1 = *reinterpret_cast<const float4*>(mask + off1);

    float a0, a1, b0, b1, c0, c1, d0, d1;
    parzen_pair(X0.x, X1.x, M0.x, M1.x, a0, a1);
    parzen_pair(X0.y, X1.y, M0.y, M1.y, b0, b1);
    parzen_pair(X0.z, X1.z, M0.z, M1.z, c0, c1);
    parzen_pair(X0.w, X1.w, M0.w, M1.w, d0, d1);

    f32x4 O0 = {a0, b0, c0, d0};
    f32x4 O1 = {a1, b1, c1, d1};
    __builtin_nontemporal_store(O0, reinterpret_cast<f32x4*>(out + off0));
    __builtin_nontemporal_store(O1, reinterpret_cast<f32x4*>(out + off1));
}

extern "C" void kernel_launch(void* const* d_in, const int* in_sizes, int n_in,
                              void* d_out, int out_size, void* d_ws, size_t ws_size,
                              hipStream_t stream) {
    const float* img  = (const float*)d_in[0];   // [2,2,1,96,96,96] f32
    const float* mask = (const float*)d_in[1];   // [2,2,96,96,96] f32
    float* out = (float*)d_out;                  // [2,2,96,96,96] f32

    int total = in_sizes[0];      // 4*V
    int V = total / 4;            // 884736 (divisible by 4)
    int threads = 2 * (V >> 2);
    int block = 256;
    int grid = (threads + block - 1) / block;
    parzen_kernel<<<grid, block, 0, stream>>>(img, mask, out, V);
}